// Round 9
// baseline (290.607 us; speedup 1.0000x reference)
//
#include <hip/hip_runtime.h>

// Sparse conv, sorted-message pipeline v7 (XCD-privatized atomics).
//   memset cnt(8MB, in d_out scratch!) ; memset none else
//   prep (fused): xcvt x->bf16 | 8-way partitioned histogram cnt[chunk&7][vox]
//                 | W -> MFMA-fragment layout (Wf)
//   scan1/2/3:    starts[vox] = exclusive prefix of per-vox totals;
//                 scan3 also writes cursor2[x][vox] = starts + prefix_x(cnt)
//   scatter:      perm[i] = atomicAdd(cursor2[(i>>8)&7][out_map[i]], 1)
//                 (partition matches histogram -> counts always consistent;
//                  atomics stay XCD-local -> no L2 line ping-pong)
//   gemm:         dist-2 pipelined gather -> bf16 MFMA -> nt msg row at perm[i]
//   gather:       in-lane contiguous segment sum; n = starts[o+1]-starts[o]
// d_out doubles as scratch for cnt/cursor2 (16MB) -- fully overwritten by gather.

typedef __attribute__((ext_vector_type(8))) short bf16x8;
typedef __attribute__((ext_vector_type(8))) unsigned short u16x8;
typedef __attribute__((ext_vector_type(4))) unsigned short u16x4;
typedef __attribute__((ext_vector_type(4))) float f32x4;
typedef __attribute__((ext_vector_type(2))) float f32x2;

constexpr int KOFF = 27;
constexpr int M = 65536;
constexpr int CIN = 64;
constexpr int COUT = 64;
constexpr int NVOX = 262144;
constexpr int NMSG = KOFF * M;                 // 1,769,472
constexpr int TM_BLOCK = 512;
constexpr int TILES_PER_K = M / TM_BLOCK;      // 128
constexpr int SUBTILES = TM_BLOCK / (4 * 16);  // 8
constexpr int XCVT_BLOCKS = NVOX * CIN / 8 / 256;  // 8192 (multiple of 8)
constexpr int COUNT_BLOCKS = NMSG / 256;           // 6912
constexpr int NPART = 8;

static __device__ __forceinline__ short f2bf(float f) {
  unsigned u = __builtin_bit_cast(unsigned, f);
  unsigned r = (u + 0x7FFFu + ((u >> 16) & 1u)) >> 16;
  return (short)r;
}
static __device__ __forceinline__ float bf2f(unsigned short h) {
  return __builtin_bit_cast(float, (unsigned)h << 16);
}

// ---------------- fused prep: xcvt | partitioned histogram | W-fragment ----------------

__global__ __launch_bounds__(256) void prep_kernel(
    const float* __restrict__ x, const float* __restrict__ W,
    const int* __restrict__ out_map, unsigned short* __restrict__ xb,
    unsigned short* __restrict__ Wf, int* __restrict__ cnt, int xcvtBlocks) {
  const int b = blockIdx.x;
  if (b < xcvtBlocks) {
    int i = b * 256 + threadIdx.x;
    const float4* p = (const float4*)x + (size_t)i * 2;
    float4 a = p[0], q = p[1];
    u16x8 h;
    h[0] = (unsigned short)f2bf(a.x); h[1] = (unsigned short)f2bf(a.y);
    h[2] = (unsigned short)f2bf(a.z); h[3] = (unsigned short)f2bf(a.w);
    h[4] = (unsigned short)f2bf(q.x); h[5] = (unsigned short)f2bf(q.y);
    h[6] = (unsigned short)f2bf(q.z); h[7] = (unsigned short)f2bf(q.w);
    *(u16x8*)(xb + (size_t)i * 8) = h;
  } else if (b < xcvtBlocks + COUNT_BLOCKS) {
    int cb = b - xcvtBlocks;                 // message chunk index
    int i = cb * 256 + threadIdx.x;
    // Partition by chunk&7: matches scatter's partition (correctness) and the
    // round-robin block->XCD mapping (performance: atomics stay XCD-local).
    atomicAdd(&cnt[(size_t)(cb & 7) * NVOX + out_map[i]], 1);
  } else {
    // W[k] -> fragment order: Wf[k][(t*2+u)*64 + l][j] = W[k][u*32+(l>>4)*8+j][t*16+(l&15)]
    int k = b - xcvtBlocks - COUNT_BLOCKS;  // 0..26
    const float* Wk = W + (size_t)k * (CIN * COUT);
    unsigned short* dst = Wf + (size_t)k * 4096;
#pragma unroll
    for (int i = 0; i < 16; ++i) {
      int e = threadIdx.x * 16 + i;
      int j = e & 7, l = (e >> 3) & 63, tu = e >> 9;
      int t = tu >> 1, u = tu & 1;
      dst[e] = (unsigned short)f2bf(Wk[(u * 32 + (l >> 4) * 8 + j) * COUT + t * 16 + (l & 15)]);
    }
  }
}

// ---------------- scan ----------------

__global__ __launch_bounds__(256) void scan1_kernel(const int* __restrict__ cnt,
                                                    int* __restrict__ starts,
                                                    int* __restrict__ blockSums) {
  __shared__ int s[256];
  int t = threadIdx.x, i = blockIdx.x * 256 + t;  // grid = 1024
  int c = 0;
#pragma unroll
  for (int xp = 0; xp < NPART; ++xp) c += cnt[(size_t)xp * NVOX + i];
  s[t] = c; __syncthreads();
  for (int off = 1; off < 256; off <<= 1) {
    int add = (t >= off) ? s[t - off] : 0;
    __syncthreads(); s[t] += add; __syncthreads();
  }
  starts[i] = s[t] - c;  // block-local exclusive
  if (t == 255) blockSums[blockIdx.x] = s[t];
}

__global__ __launch_bounds__(256) void scan2_kernel(int* __restrict__ bs) {
  __shared__ int s[256];
  int t = threadIdx.x;
  int v0 = bs[t*4], v1 = bs[t*4+1], v2 = bs[t*4+2], v3 = bs[t*4+3];
  int sum = v0 + v1 + v2 + v3;
  s[t] = sum; __syncthreads();
  for (int off = 1; off < 256; off <<= 1) {
    int add = (t >= off) ? s[t - off] : 0;
    __syncthreads(); s[t] += add; __syncthreads();
  }
  int run = s[t] - sum;
  bs[t*4] = run; run += v0;
  bs[t*4+1] = run; run += v1;
  bs[t*4+2] = run; run += v2;
  bs[t*4+3] = run;
}

__global__ __launch_bounds__(256) void scan3_kernel(int* __restrict__ starts,
                                                    const int* __restrict__ blockBase,
                                                    const int* __restrict__ cnt,
                                                    int* __restrict__ cursor2) {
  int i = blockIdx.x * 256 + threadIdx.x;  // grid = 1024, one thread per voxel
  int s = starts[i] + blockBase[blockIdx.x];
  starts[i] = s;                           // global segment start
  int run = s;
#pragma unroll
  for (int xp = 0; xp < NPART; ++xp) {     // per-partition sub-range bases
    cursor2[(size_t)xp * NVOX + i] = run;
    run += cnt[(size_t)xp * NVOX + i];
  }
  if (i == 0) starts[NVOX] = NMSG;         // sentinel for n-derivation
}

// ---------------- scatter: perm[i] = sorted slot (partitioned atomics) --------

__global__ __launch_bounds__(256) void scatter_kernel(const int* __restrict__ out_map,
                                                      int* __restrict__ cursor2,
                                                      int* __restrict__ perm) {
  int i = blockIdx.x * 256 + threadIdx.x;  // grid = NMSG/256
  int xp = blockIdx.x & 7;                 // == (i>>8)&7, matches histogram
  perm[i] = atomicAdd(&cursor2[(size_t)xp * NVOX + out_map[i]], 1);
}

// ---------------- phase A: pipelined GEMM -> nt msg at sorted slots ----------------

template <bool BF16IN>
__global__ __launch_bounds__(256) void gemm_msg_kernel(
    const void* __restrict__ xin, const unsigned short* __restrict__ Wf,
    const int* __restrict__ in_map, const int* __restrict__ perm,
    unsigned short* __restrict__ msg) {
  const int k = blockIdx.x / TILES_PER_K;
  const int mblock = (blockIdx.x % TILES_PER_K) * TM_BLOCK;
  const int wave = threadIdx.x >> 6;
  const int l = threadIdx.x & 63;
  const int lg = l >> 4;
  const int lr = l & 15;

  bf16x8 bfrag[4][2];
  const bf16x8* wf = (const bf16x8*)(Wf + (size_t)k * 4096);
#pragma unroll
  for (int t = 0; t < 4; ++t)
#pragma unroll
    for (int u = 0; u < 2; ++u)
      bfrag[t][u] = wf[(t * 2 + u) * 64 + l];

  const int mwave = mblock + wave * (TM_BLOCK / 4);
  const int rb = k * M + mwave;

  auto loadA = [&](int s, bf16x8& A0, bf16x8& A1) {
    int id = in_map[rb + s * 16 + lr];
    if (BF16IN) {
      const unsigned short* xr = (const unsigned short*)xin + (size_t)id * CIN + lg * 8;
      A0 = *(const bf16x8*)(xr);
      A1 = *(const bf16x8*)(xr + 32);
    } else {
      const float* xr = (const float*)xin + (size_t)id * CIN + lg * 8;
      float4 x0 = *(const float4*)(xr);
      float4 x1 = *(const float4*)(xr + 4);
      float4 x2 = *(const float4*)(xr + 32);
      float4 x3 = *(const float4*)(xr + 36);
      A0[0]=f2bf(x0.x); A0[1]=f2bf(x0.y); A0[2]=f2bf(x0.z); A0[3]=f2bf(x0.w);
      A0[4]=f2bf(x1.x); A0[5]=f2bf(x1.y); A0[6]=f2bf(x1.z); A0[7]=f2bf(x1.w);
      A1[0]=f2bf(x2.x); A1[1]=f2bf(x2.y); A1[2]=f2bf(x2.z); A1[3]=f2bf(x2.w);
      A1[4]=f2bf(x3.x); A1[5]=f2bf(x3.y); A1[6]=f2bf(x3.z); A1[7]=f2bf(x3.w);
    }
  };

  bf16x8 c0, c1, n0, n1;
  loadA(0, c0, c1);
  loadA(1, n0, n1);

#pragma unroll 1
  for (int s = 0; s < SUBTILES; ++s) {
    bf16x8 p0, p1;
    const bool have = (s + 2 < SUBTILES);
    if (have) loadA(s + 2, p0, p1);

    f32x4 acc[4] = {{0.f,0.f,0.f,0.f},{0.f,0.f,0.f,0.f},{0.f,0.f,0.f,0.f},{0.f,0.f,0.f,0.f}};
#pragma unroll
    for (int t = 0; t < 4; ++t) {
      acc[t] = __builtin_amdgcn_mfma_f32_16x16x32_bf16(c0, bfrag[t][0], acc[t], 0, 0, 0);
      acc[t] = __builtin_amdgcn_mfma_f32_16x16x32_bf16(c1, bfrag[t][1], acc[t], 0, 0, 0);
    }

    // Row layout: position p = lr*4 + t holds channel t*16 + lr.
    const int* pr = perm + rb + s * 16 + lg * 4;
#pragma unroll
    for (int r = 0; r < 4; ++r) {
      const int sl = pr[r];
      u16x4 h;
      h[0] = (unsigned short)f2bf(acc[0][r]);
      h[1] = (unsigned short)f2bf(acc[1][r]);
      h[2] = (unsigned short)f2bf(acc[2][r]);
      h[3] = (unsigned short)f2bf(acc[3][r]);
      __builtin_nontemporal_store(h, (u16x4*)(msg + (size_t)sl * 64 + lr * 4));
    }

    c0 = n0; c1 = n1;
    if (have) { n0 = p0; n1 = p1; }
  }
}

// ---------------- phase B: in-lane contiguous segment sum ----------------

__global__ __launch_bounds__(256) void gather_out_kernel(
    const unsigned short* __restrict__ msg, const int* __restrict__ starts,
    float* __restrict__ out) {
  const int wid = (blockIdx.x * 256 + threadIdx.x) >> 6;  // grid = NVOX/32 blocks
  const int p = threadIdx.x & 63;
  const int r = p >> 3;   // which of this wave's 8 output rows
  const int c = p & 7;    // 16B chunk within the 128B msg row
  const int o = wid * 8 + r;

  const int base = starts[o];
  const int n = starts[o + 1] - base;  // sentinel starts[NVOX] = NMSG
  const unsigned short* src = msg + (size_t)base * 64 + c * 8;

  u16x8 v[8];
#pragma unroll
  for (int i = 0; i < 8; ++i) {
    int safe = (i < n) ? i : 0;
    v[i] = __builtin_nontemporal_load((const u16x8*)(src + (size_t)safe * 64));
  }
  float acc[8] = {};
#pragma unroll
  for (int i = 0; i < 8; ++i) {
    float m = (i < n) ? 1.0f : 0.0f;
#pragma unroll
    for (int d = 0; d < 8; ++d)
      acc[d] = fmaf(m, bf2f((unsigned short)v[i][d]), acc[d]);
  }
  for (int i = 8; i < n; ++i) {
    u16x8 t = __builtin_nontemporal_load((const u16x8*)(src + (size_t)i * 64));
#pragma unroll
    for (int d = 0; d < 8; ++d) acc[d] += bf2f((unsigned short)t[d]);
  }

  // position q = c*8 + d -> channel (d&3)*16 + 2c + (d>>2); all 64 lanes store.
  float* orow = out + (size_t)o * 64 + 2 * c;
  f32x2 s0 = {acc[0], acc[4]};
  f32x2 s1 = {acc[1], acc[5]};
  f32x2 s2 = {acc[2], acc[6]};
  f32x2 s3 = {acc[3], acc[7]};
  __builtin_nontemporal_store(s0, (f32x2*)(orow));
  __builtin_nontemporal_store(s1, (f32x2*)(orow + 16));
  __builtin_nontemporal_store(s2, (f32x2*)(orow + 32));
  __builtin_nontemporal_store(s3, (f32x2*)(orow + 48));
}

// ---------------- fallback (atomic scatter) ----------------

__global__ __launch_bounds__(256) void spconv_atomic_kernel(
    const float* __restrict__ x, const float* __restrict__ W,
    const int* __restrict__ in_map, const int* __restrict__ out_map,
    float* __restrict__ out) {
  const int k = blockIdx.x / TILES_PER_K;
  const int mblock = (blockIdx.x % TILES_PER_K) * TM_BLOCK;
  const int wave = threadIdx.x >> 6;
  const int l = threadIdx.x & 63;
  const int lg = l >> 4;
  const int lr = l & 15;
  bf16x8 bfrag[4][2];
  const float* Wk = W + (size_t)k * (CIN * COUT);
#pragma unroll
  for (int t = 0; t < 4; ++t)
#pragma unroll
    for (int u = 0; u < 2; ++u)
#pragma unroll
      for (int j = 0; j < 8; ++j)
        bfrag[t][u][j] = f2bf(Wk[(u * 32 + lg * 8 + j) * COUT + t * 16 + lr]);
  const int mwave = mblock + wave * (TM_BLOCK / 4);
#pragma unroll 1
  for (int s = 0; s < SUBTILES; ++s) {
    const int mbase = mwave + s * 16;
    const int in_idx = in_map[k * M + mbase + lr];
    const float* xr = x + (size_t)in_idx * CIN + lg * 8;
    float4 x0 = *(const float4*)(xr);
    float4 x1 = *(const float4*)(xr + 4);
    float4 x2 = *(const float4*)(xr + 32);
    float4 x3 = *(const float4*)(xr + 36);
    bf16x8 a0, a1;
    a0[0]=f2bf(x0.x); a0[1]=f2bf(x0.y); a0[2]=f2bf(x0.z); a0[3]=f2bf(x0.w);
    a0[4]=f2bf(x1.x); a0[5]=f2bf(x1.y); a0[6]=f2bf(x1.z); a0[7]=f2bf(x1.w);
    a1[0]=f2bf(x2.x); a1[1]=f2bf(x2.y); a1[2]=f2bf(x2.z); a1[3]=f2bf(x2.w);
    a1[4]=f2bf(x3.x); a1[5]=f2bf(x3.y); a1[6]=f2bf(x3.z); a1[7]=f2bf(x3.w);
    f32x4 acc[4] = {{0.f,0.f,0.f,0.f},{0.f,0.f,0.f,0.f},{0.f,0.f,0.f,0.f},{0.f,0.f,0.f,0.f}};
#pragma unroll
    for (int t = 0; t < 4; ++t) {
      acc[t] = __builtin_amdgcn_mfma_f32_16x16x32_bf16(a0, bfrag[t][0], acc[t], 0, 0, 0);
      acc[t] = __builtin_amdgcn_mfma_f32_16x16x32_bf16(a1, bfrag[t][1], acc[t], 0, 0, 0);
    }
    const int obase = k * M + mbase + lg * 4;
    int oidx[4];
#pragma unroll
    for (int r = 0; r < 4; ++r) oidx[r] = out_map[obase + r];
#pragma unroll
    for (int t = 0; t < 4; ++t)
#pragma unroll
      for (int r = 0; r < 4; ++r)
        atomicAdd(out + (size_t)oidx[r] * COUT + t * 16 + lr, acc[t][r]);
  }
}

extern "C" void kernel_launch(void* const* d_in, const int* in_sizes, int n_in,
                              void* d_out, int out_size, void* d_ws, size_t ws_size,
                              hipStream_t stream) {
  const float* x = (const float*)d_in[0];
  const float* W = (const float*)d_in[1];
  const int* in_map = (const int*)d_in[2];
  const int* out_map = (const int*)d_in[3];
  float* out = (float*)d_out;
  char* ws = (char*)d_ws;

  const size_t msg_b    = (size_t)NMSG * 128;        // 226,492,416
  const size_t xb_b     = (size_t)NVOX * CIN * 2;    //  33,554,432
  const size_t perm_b   = (size_t)NMSG * 4;          //   7,077,888
  const size_t wf_b     = (size_t)KOFF * 4096 * 2;   //     221,184
  const size_t starts_b = (size_t)(NVOX + 1) * 4;    //   1,048,580
  const size_t bs_b     = 1024 * 4;
  const size_t part_b   = (size_t)NPART * NVOX * 4;  //   8 MB (cnt / cursor2)
  auto pad = [](size_t b) { return (b + 255) & ~(size_t)255; };

  size_t need_p1 = pad(msg_b) + pad(perm_b) + pad(wf_b) + pad(starts_b) + pad(bs_b);
  size_t need_p0 = need_p1 + pad(xb_b);
  bool useXb = (ws_size >= need_p0);

  // cnt/cursor2 (16MB) live in d_out scratch; need d_out >= 16MB (it is 67MB).
  bool outScratchOk = ((size_t)out_size * 4 >= 2 * part_b);

  if (ws_size < need_p1 || !outScratchOk) {
    hipMemsetAsync(d_out, 0, (size_t)out_size * sizeof(float), stream);
    spconv_atomic_kernel<<<dim3(KOFF * TILES_PER_K), dim3(256), 0, stream>>>(
        x, W, in_map, out_map, out);
    return;
  }

  size_t off = 0;
  unsigned short* msg = (unsigned short*)(ws + off); off += pad(msg_b);
  unsigned short* xb = nullptr;
  if (useXb) { xb = (unsigned short*)(ws + off); off += pad(xb_b); }
  int* perm = (int*)(ws + off); off += pad(perm_b);
  unsigned short* Wf = (unsigned short*)(ws + off); off += pad(wf_b);
  int* starts = (int*)(ws + off); off += pad(starts_b);
  int* bsum   = (int*)(ws + off);

  int* cnt     = (int*)d_out;                      // 8MB scratch in d_out
  int* cursor2 = (int*)d_out + (size_t)NPART * NVOX;  // next 8MB

  hipMemsetAsync(cnt, 0, part_b, stream);

  int xcvtBlocks = useXb ? XCVT_BLOCKS : 0;
  prep_kernel<<<dim3(xcvtBlocks + COUNT_BLOCKS + KOFF), dim3(256), 0, stream>>>(
      x, W, out_map, xb, Wf, cnt, xcvtBlocks);

  scan1_kernel<<<dim3(NVOX / 256), dim3(256), 0, stream>>>(cnt, starts, bsum);
  scan2_kernel<<<dim3(1), dim3(256), 0, stream>>>(bsum);
  scan3_kernel<<<dim3(NVOX / 256), dim3(256), 0, stream>>>(starts, bsum, cnt, cursor2);
  scatter_kernel<<<dim3(NMSG / 256), dim3(256), 0, stream>>>(out_map, cursor2, perm);

  if (useXb)
    gemm_msg_kernel<true><<<dim3(KOFF * TILES_PER_K), dim3(256), 0, stream>>>(
        (const void*)xb, Wf, in_map, perm, msg);
  else
    gemm_msg_kernel<false><<<dim3(KOFF * TILES_PER_K), dim3(256), 0, stream>>>(
        (const void*)x, Wf, in_map, perm, msg);

  gather_out_kernel<<<dim3(NVOX / 32), dim3(256), 0, stream>>>(msg, starts, out);
}

// Round 10
// 228.117 us; speedup vs baseline: 1.2739x; 1.2739x over previous
//
#include <hip/hip_runtime.h>

// Sparse conv, sorted-message pipeline v8 (single atomic pass).  See header
// comments above each kernel. Structure:
//   memset cnt (1MB, d_out scratch) ; xw (xcvt + Wf) ; rank (ONE atomic pass:
//   rank[i]=atomicAdd(cnt[out],1), cnt becomes histogram) ; scan1/2/3 ->
//   starts ; gemm (slot = starts[out]+rank, nt msg stores) ; gather.

typedef __attribute__((ext_vector_type(8))) short bf16x8;
typedef __attribute__((ext_vector_type(8))) unsigned short u16x8;
typedef __attribute__((ext_vector_type(4))) unsigned short u16x4;
typedef __attribute__((ext_vector_type(4))) float f32x4;
typedef __attribute__((ext_vector_type(2))) float f32x2;

constexpr int KOFF = 27;
constexpr int M = 65536;
constexpr int CIN = 64;
constexpr int COUT = 64;
constexpr int NVOX = 262144;
constexpr int NMSG = KOFF * M;
constexpr int TM_BLOCK = 512;
constexpr int TILES_PER_K = M / TM_BLOCK;
constexpr int SUBTILES = TM_BLOCK / (4 * 16);
constexpr int XCVT_BLOCKS = NVOX * CIN / 8 / 256;

static __device__ __forceinline__ short f2bf(float f) {
  unsigned u = __builtin_bit_cast(unsigned, f);
  unsigned r = (u + 0x7FFFu + ((u >> 16) & 1u)) >> 16;
  return (short)r;
}
static __device__ __forceinline__ float bf2f(unsigned short h) {
  return __builtin_bit_cast(float, (unsigned)h << 16);
}

__global__ __launch_bounds__(256) void xw_kernel(
    const float* __restrict__ x, const float* __restrict__ W,
    unsigned short* __restrict__ xb, unsigned short* __restrict__ Wf,
    int xcvtBlocks) {
  const int b = blockIdx.x;
  if (b < xcvtBlocks) {
    int i = b * 256 + threadIdx.x;
    const float4* p = (const float4*)x + (size_t)i * 2;
    float4 a = p[0], q = p[1];
    u16x8 h;
    h[0] = (unsigned short)f2bf(a.x); h[1] = (unsigned short)f2bf(a.y);
    h[2] = (unsigned short)f2bf(a.z); h[3] = (unsigned short)f2bf(a.w);
    h[4] = (unsigned short)f2bf(q.x); h[5] = (unsigned short)f2bf(q.y);
    h[6] = (unsigned short)f2bf(q.z); h[7] = (unsigned short)f2bf(q.w);
    *(u16x8*)(xb + (size_t)i * 8) = h;
  } else {
    int k = b - xcvtBlocks;  // 0..26
    const float* Wk = W + (size_t)k * (CIN * COUT);
    unsigned short* dst = Wf + (size_t)k * 4096;
#pragma unroll
    for (int i = 0; i < 16; ++i) {
      int e = threadIdx.x * 16 + i;
      int j = e & 7, l = (e >> 3) & 63, tu = e >> 9;
      int t = tu >> 1, u = tu & 1;
      dst[e] = (unsigned short)f2bf(Wk[(u * 32 + (l >> 4) * 8 + j) * COUT + t * 16 + (l & 15)]);
    }
  }
}

__global__ __launch_bounds__(256) void rank_kernel(const int* __restrict__ out_map,
                                                   int* __restrict__ cnt,
                                                   int* __restrict__ rank) {
  int i = (blockIdx.x * 256 + threadIdx.x) * 4;  // grid = NMSG/1024 = 1728
  int4 om = *(const int4*)(out_map + i);
  int4 rk;
  rk.x = atomicAdd(&cnt[om.x], 1);
  rk.y = atomicAdd(&cnt[om.y], 1);
  rk.z = atomicAdd(&cnt[om.z], 1);
  rk.w = atomicAdd(&cnt[om.w], 1);
  *(int4*)(rank + i) = rk;
}

__global__ __launch_bounds__(256) void scan1_kernel(const int* __restrict__ cnt,
                                                    int* __restrict__ starts,
                                                    int* __restrict__ blockSums) {
  __shared__ int s[256];
  int t = threadIdx.x, i = blockIdx.x * 256 + t;
  int c = cnt[i];
  s[t] = c; __syncthreads();
  for (int off = 1; off < 256; off <<= 1) {
    int add = (t >= off) ? s[t - off] : 0;
    __syncthreads(); s[t] += add; __syncthreads();
  }
  starts[i] = s[t] - c;
  if (t == 255) blockSums[blockIdx.x] = s[t];
}

__global__ __launch_bounds__(256) void scan2_kernel(int* __restrict__ bs) {
  __shared__ int s[256];
  int t = threadIdx.x;
  int v0 = bs[t*4], v1 = bs[t*4+1], v2 = bs[t*4+2], v3 = bs[t*4+3];
  int sum = v0 + v1 + v2 + v3;
  s[t] = sum; __syncthreads();
  for (int off = 1; off < 256; off <<= 1) {
    int add = (t >= off) ? s[t - off] : 0;
    __syncthreads(); s[t] += add; __syncthreads();
  }
  int run = s[t] - sum;
  bs[t*4] = run; run += v0;
  bs[t*4+1] = run; run += v1;
  bs[t*4+2] = run; run += v2;
  bs[t*4+3] = run;
}

__global__ __launch_bounds__(256) void scan3_kernel(int* __restrict__ starts,
                                                    const int* __restrict__ blockBase) {
  int i = blockIdx.x * 256 + threadIdx.x;
  starts[i] += blockBase[blockIdx.x];
  if (i == 0) starts[NVOX] = NMSG;
}

template <bool BF16IN>
__global__ __launch_bounds__(256) void gemm_msg_kernel(
    const void* __restrict__ xin, const unsigned short* __restrict__ Wf,
    const int* __restrict__ in_map, const int* __restrict__ out_map,
    const int* __restrict__ rank, const int* __restrict__ starts,
    unsigned short* __restrict__ msg) {
  const int k = blockIdx.x / TILES_PER_K;
  const int mblock = (blockIdx.x % TILES_PER_K) * TM_BLOCK;
  const int wave = threadIdx.x >> 6;
  const int l = threadIdx.x & 63;
  const int lg = l >> 4;
  const int lr = l & 15;

  bf16x8 bfrag[4][2];
  const bf16x8* wf = (const bf16x8*)(Wf + (size_t)k * 4096);
#pragma unroll
  for (int t = 0; t < 4; ++t)
#pragma unroll
    for (int u = 0; u < 2; ++u)
      bfrag[t][u] = wf[(t * 2 + u) * 64 + l];

  const int mwave = mblock + wave * (TM_BLOCK / 4);
  const int rb = k * M + mwave;

  auto loadA = [&](int s, bf16x8& A0, bf16x8& A1) {
    int id = in_map[rb + s * 16 + lr];
    if (BF16IN) {
      const unsigned short* xr = (const unsigned short*)xin + (size_t)id * CIN + lg * 8;
      A0 = *(const bf16x8*)(xr);
      A1 = *(const bf16x8*)(xr + 32);
    } else {
      const float* xr = (const float*)xin + (size_t)id * CIN + lg * 8;
      float4 x0 = *(const float4*)(xr);
      float4 x1 = *(const float4*)(xr + 4);
      float4 x2 = *(const float4*)(xr + 32);
      float4 x3 = *(const float4*)(xr + 36);
      A0[0]=f2bf(x0.x); A0[1]=f2bf(x0.y); A0[2]=f2bf(x0.z); A0[3]=f2bf(x0.w);
      A0[4]=f2bf(x1.x); A0[5]=f2bf(x1.y); A0[6]=f2bf(x1.z); A0[7]=f2bf(x1.w);
      A1[0]=f2bf(x2.x); A1[1]=f2bf(x2.y); A1[2]=f2bf(x2.z); A1[3]=f2bf(x2.w);
      A1[4]=f2bf(x3.x); A1[5]=f2bf(x3.y); A1[6]=f2bf(x3.z); A1[7]=f2bf(x3.w);
    }
  };

  int om[4], rk[4];
#pragma unroll
  for (int r = 0; r < 4; ++r) {
    om[r] = out_map[rb + lg * 4 + r];
    rk[r] = rank[rb + lg * 4 + r];
  }

  bf16x8 c0, c1, n0, n1;
  loadA(0, c0, c1);
  loadA(1, n0, n1);

#pragma unroll 1
  for (int s = 0; s < SUBTILES; ++s) {
    bf16x8 p0, p1;
    const bool have = (s + 2 < SUBTILES);
    if (have) loadA(s + 2, p0, p1);

    int omN[4], rkN[4];
    if (s + 1 < SUBTILES) {
      const int rowb = rb + (s + 1) * 16 + lg * 4;
#pragma unroll
      for (int r = 0; r < 4; ++r) { omN[r] = out_map[rowb + r]; rkN[r] = rank[rowb + r]; }
    } else {
#pragma unroll
      for (int r = 0; r < 4; ++r) { omN[r] = 0; rkN[r] = 0; }
    }
    int st[4];
#pragma unroll
    for (int r = 0; r < 4; ++r) st[r] = starts[om[r]];

    f32x4 acc[4] = {{0.f,0.f,0.f,0.f},{0.f,0.f,0.f,0.f},{0.f,0.f,0.f,0.f},{0.f,0.f,0.f,0.f}};
#pragma unroll
    for (int t = 0; t < 4; ++t) {
      acc[t] = __builtin_amdgcn_mfma_f32_16x16x32_bf16(c0, bfrag[t][0], acc[t], 0, 0, 0);
      acc[t] = __builtin_amdgcn_mfma_f32_16x16x32_bf16(c1, bfrag[t][1], acc[t], 0, 0, 0);
    }

#pragma unroll
    for (int r = 0; r < 4; ++r) {
      const int sl = st[r] + rk[r];
      u16x4 h;
      h[0] = (unsigned short)f2bf(acc[0][r]);
      h[1] = (unsigned short)f2bf(acc[1][r]);
      h[2] = (unsigned short)f2bf(acc[2][r]);
      h[3] = (unsigned short)f2bf(acc[3][r]);
      __builtin_nontemporal_store(h, (u16x4*)(msg + (size_t)sl * 64 + lr * 4));
    }

    c0 = n0; c1 = n1;
    if (have) { n0 = p0; n1 = p1; }
#pragma unroll
    for (int r = 0; r < 4; ++r) { om[r] = omN[r]; rk[r] = rkN[r]; }
  }
}

__global__ __launch_bounds__(256) void gather_out_kernel(
    const unsigned short* __restrict__ msg, const int* __restrict__ starts,
    float* __restrict__ out) {
  const int wid = (blockIdx.x * 256 + threadIdx.x) >> 6;
  const int p = threadIdx.x & 63;
  const int r = p >> 3;
  const int c = p & 7;
  const int o = wid * 8 + r;

  const int base = starts[o];
  const int n = starts[o + 1] - base;
  const unsigned short* src = msg + (size_t)base * 64 + c * 8;

  u16x8 v[8];
#pragma unroll
  for (int i = 0; i < 8; ++i) {
    int safe = (i < n) ? i : 0;
    v[i] = __builtin_nontemporal_load((const u16x8*)(src + (size_t)safe * 64));
  }
  float acc[8] = {};
#pragma unroll
  for (int i = 0; i < 8; ++i) {
    float m = (i < n) ? 1.0f : 0.0f;
#pragma unroll
    for (int d = 0; d < 8; ++d)
      acc[d] = fmaf(m, bf2f((unsigned short)v[i][d]), acc[d]);
  }
  for (int i = 8; i < n; ++i) {
    u16x8 t = __builtin_nontemporal_load((const u16x8*)(src + (size_t)i * 64));
#pragma unroll
    for (int d = 0; d < 8; ++d) acc[d] += bf2f((unsigned short)t[d]);
  }

  float* orow = out + (size_t)o * 64 + 2 * c;
  f32x2 s0 = {acc[0], acc[4]};
  f32x2 s1 = {acc[1], acc[5]};
  f32x2 s2 = {acc[2], acc[6]};
  f32x2 s3 = {acc[3], acc[7]};
  __builtin_nontemporal_store(s0, (f32x2*)(orow));
  __builtin_nontemporal_store(s1, (f32x2*)(orow + 16));
  __builtin_nontemporal_store(s2, (f32x2*)(orow + 32));
  __builtin_nontemporal_store(s3, (f32x2*)(orow + 48));
}

__global__ __launch_bounds__(256) void spconv_atomic_kernel(
    const float* __restrict__ x, const float* __restrict__ W,
    const int* __restrict__ in_map, const int* __restrict__ out_map,
    float* __restrict__ out) {
  const int k = blockIdx.x / TILES_PER_K;
  const int mblock = (blockIdx.x % TILES_PER_K) * TM_BLOCK;
  const int wave = threadIdx.x >> 6;
  const int l = threadIdx.x & 63;
  const int lg = l >> 4;
  const int lr = l & 15;
  bf16x8 bfrag[4][2];
  const float* Wk = W + (size_t)k * (CIN * COUT);
#pragma unroll
  for (int t = 0; t < 4; ++t)
#pragma unroll
    for (int u = 0; u < 2; ++u)
#pragma unroll
      for (int j = 0; j < 8; ++j)
        bfrag[t][u][j] = f2bf(Wk[(u * 32 + lg * 8 + j) * COUT + t * 16 + lr]);
  const int mwave = mblock + wave * (TM_BLOCK / 4);
#pragma unroll 1
  for (int s = 0; s < SUBTILES; ++s) {
    const int mbase = mwave + s * 16;
    const int in_idx = in_map[k * M + mbase + lr];
    const float* xr = x + (size_t)in_idx * CIN + lg * 8;
    float4 x0 = *(const float4*)(xr);
    float4 x1 = *(const float4*)(xr + 4);
    float4 x2 = *(const float4*)(xr + 32);
    float4 x3 = *(const float4*)(xr + 36);
    bf16x8 a0, a1;
    a0[0]=f2bf(x0.x); a0[1]=f2bf(x0.y); a0[2]=f2bf(x0.z); a0[3]=f2bf(x0.w);
    a0[4]=f2bf(x1.x); a0[5]=f2bf(x1.y); a0[6]=f2bf(x1.z); a0[7]=f2bf(x1.w);
    a1[0]=f2bf(x2.x); a1[1]=f2bf(x2.y); a1[2]=f2bf(x2.z); a1[3]=f2bf(x2.w);
    a1[4]=f2bf(x3.x); a1[5]=f2bf(x3.y); a1[6]=f2bf(x3.z); a1[7]=f2bf(x3.w);
    f32x4 acc[4] = {{0.f,0.f,0.f,0.f},{0.f,0.f,0.f,0.f},{0.f,0.f,0.f,0.f},{0.f,0.f,0.f,0.f}};
#pragma unroll
    for (int t = 0; t < 4; ++t) {
      acc[t] = __builtin_amdgcn_mfma_f32_16x16x32_bf16(a0, bfrag[t][0], acc[t], 0, 0, 0);
      acc[t] = __builtin_amdgcn_mfma_f32_16x16x32_bf16(a1, bfrag[t][1], acc[t], 0, 0, 0);
    }
    const int obase = k * M + mbase + lg * 4;
    int oidx[4];
#pragma unroll
    for (int r = 0; r < 4; ++r) oidx[r] = out_map[obase + r];
#pragma unroll
    for (int t = 0; t < 4; ++t)
#pragma unroll
      for (int r = 0; r < 4; ++r)
        atomicAdd(out + (size_t)oidx[r] * COUT + t * 16 + lr, acc[t][r]);
  }
}

extern "C" void kernel_launch(void* const* d_in, const int* in_sizes, int n_in,
                              void* d_out, int out_size, void* d_ws, size_t ws_size,
                              hipStream_t stream) {
  const float* x = (const float*)d_in[0];
  const float* W = (const float*)d_in[1];
  const int* in_map = (const int*)d_in[2];
  const int* out_map = (const int*)d_in[3];
  float* out = (float*)d_out;
  char* ws = (char*)d_ws;

  const size_t msg_b    = (size_t)NMSG * 128;
  const size_t xb_b     = (size_t)NVOX * CIN * 2;
  const size_t rank_b   = (size_t)NMSG * 4;
  const size_t wf_b     = (size_t)KOFF * 4096 * 2;
  const size_t starts_b = (size_t)(NVOX + 1) * 4;
  const size_t cnt_b    = (size_t)NVOX * 4;
  auto pad = [](size_t b) { return (b + 255) & ~(size_t)255; };

  size_t need_p1 = pad(msg_b) + pad(rank_b) + pad(wf_b) + pad(starts_b);
  size_t need_p0 = need_p1 + pad(xb_b);  // 268,394,752 B
  bool useXb = (ws_size >= need_p0);
  bool outScratchOk = ((size_t)out_size * 4 >= cnt_b + 1024 * 4 + 256);

  if (ws_size < need_p1 || !outScratchOk) {
    hipMemsetAsync(d_out, 0, (size_t)out_size * sizeof(float), stream);
    spconv_atomic_kernel<<<dim3(KOFF * TILES_PER_K), dim3(256), 0, stream>>>(
        x, W, in_map, out_map, out);
    return;
  }

  size_t off = 0;
  unsigned short* msg = (unsigned short*)(ws + off); off += pad(msg_b);
  unsigned short* xb = nullptr;
  if (useXb) { xb = (unsigned short*)(ws + off); off += pad(xb_b); }
  int* rank = (int*)(ws + off); off += pad(rank_b);
  unsigned short* Wf = (unsigned short*)(ws + off); off += pad(wf_b);
  int* starts = (int*)(ws + off); off += pad(starts_b);

  int* cnt  = (int*)d_out;
  int* bsum = (int*)d_out + NVOX;

  hipMemsetAsync(cnt, 0, cnt_b, stream);

  int xcvtBlocks = useXb ? XCVT_BLOCKS : 0;
  xw_kernel<<<dim3(xcvtBlocks + KOFF), dim3(256), 0, stream>>>(x, W, xb, Wf, xcvtBlocks);

  rank_kernel<<<dim3(NMSG / 1024), dim3(256), 0, stream>>>(out_map, cnt, rank);

  scan1_kernel<<<dim3(NVOX / 256), dim3(256), 0, stream>>>(cnt, starts, bsum);
  scan2_kernel<<<dim3(1), dim3(256), 0, stream>>>(bsum);
  scan3_kernel<<<dim3(NVOX / 256), dim3(256), 0, stream>>>(starts, bsum);

  if (useXb)
    gemm_msg_kernel<true><<<dim3(KOFF * TILES_PER_K), dim3(256), 0, stream>>>(
        (const void*)xb, Wf, in_map, out_map, rank, starts, msg);
  else
    gemm_msg_kernel<false><<<dim3(KOFF * TILES_PER_K), dim3(256), 0, stream>>>(
        (const void*)x, Wf, in_map, out_map, rank, starts, msg);

  gather_out_kernel<<<dim3(NVOX / 32), dim3(256), 0, stream>>>(msg, starts, out);
}